// Round 7
// baseline (307.398 us; speedup 1.0000x reference)
//
#include <hip/hip_runtime.h>
#include <hip/hip_bf16.h>

#define SCALE 0.07216878364870322f   // (3*64)^-0.5
#define LOG2E 1.4426950408889634f
// Q is pre-scaled by SCALE*LOG2E so attention logits are in log2 units.

typedef __bf16 bf16x8 __attribute__((ext_vector_type(8)));
typedef float f32x16 __attribute__((ext_vector_type(16)));
typedef float f32x4v __attribute__((ext_vector_type(4)));
typedef unsigned int u32x4 __attribute__((ext_vector_type(4)));
typedef unsigned short u16;

#define MFMA(a, b, c) __builtin_amdgcn_mfma_f32_32x32x16_bf16(a, b, c, 0, 0, 0)

__device__ __forceinline__ u16 b16(float v) { return __builtin_bit_cast(u16, (__bf16)v); }
__device__ __forceinline__ float fb16(u16 u) {
    unsigned int t = (unsigned int)u << 16;
    return __builtin_bit_cast(float, t);
}
__device__ __forceinline__ unsigned int splitpack(float v) {
    u16 h = b16(v);
    float r = v - fb16(h);
    return (unsigned int)h | ((unsigned int)b16(r) << 16);
}
__device__ __forceinline__ unsigned int pack2(float a, float b) {
    return (unsigned int)b16(a) | ((unsigned int)b16(b) << 16);
}
__device__ __forceinline__ void gload16(const void* g, void* l) {
    __builtin_amdgcn_global_load_lds((const __attribute__((address_space(1))) void*)g,
                                     (__attribute__((address_space(3))) void*)l, 16, 0, 0);
}

// ---------------- K1: QKV projection, MFMA split-bf16, zero-LDS main loop ----
__global__ __launch_bounds__(256) void qkv_mfma(const float* __restrict__ x,
                                                const float* __restrict__ wq,
                                                u16* __restrict__ Qhi, u16* __restrict__ Qlo,
                                                u16* __restrict__ Khi, u16* __restrict__ Klo,
                                                u16* __restrict__ Vf) {
    __shared__ unsigned int ldsr[2][32][196];
    const int tid = threadIdx.x;
    const int lane = tid & 63, w = tid >> 6, hf = lane >> 5, l31 = lane & 31;
    const int o0 = blockIdx.x * 64;
    const int n0 = blockIdx.y * 128;
    const int b = blockIdx.z;
    const int nw0 = n0 + w * 32;
    const int part = o0 >> 9;
    const int h = (o0 >> 6) & 7;
    const int bh = b * 8 + h;

    const float* xp = x + ((size_t)(b * 2048 + nw0 + l31)) * 768 + hf * 24;
    const float* wp0 = wq + (size_t)(o0 + l31) * 256 + hf * 8;
    const float* wp1 = wp0 + 32 * 256;

    f32x16 acc[3][2] = {};
    #pragma unroll 2
    for (int k0 = 0; k0 < 16; ++k0) {
        float xf[24], wf0[8], wf1[8];
        #pragma unroll
        for (int q = 0; q < 6; ++q) {
            f32x4v t = *(const f32x4v*)(xp + k0 * 48 + q * 4);
            xf[q * 4 + 0] = t[0]; xf[q * 4 + 1] = t[1];
            xf[q * 4 + 2] = t[2]; xf[q * 4 + 3] = t[3];
        }
        {
            f32x4v t0 = *(const f32x4v*)(wp0 + k0 * 16);
            f32x4v t1 = *(const f32x4v*)(wp0 + k0 * 16 + 4);
            f32x4v t2 = *(const f32x4v*)(wp1 + k0 * 16);
            f32x4v t3 = *(const f32x4v*)(wp1 + k0 * 16 + 4);
            #pragma unroll
            for (int e = 0; e < 4; ++e) {
                wf0[e] = t0[e]; wf0[4 + e] = t1[e];
                wf1[e] = t2[e]; wf1[4 + e] = t3[e];
            }
        }
        bf16x8 xh[3], xl[3], wh[2], wl[2];
        #pragma unroll
        for (int c = 0; c < 3; ++c)
            #pragma unroll
            for (int e = 0; e < 8; ++e) {
                float v = xf[e * 3 + c];
                __bf16 hi = (__bf16)v;
                xh[c][e] = hi;
                xl[c][e] = (__bf16)(v - (float)hi);
            }
        #pragma unroll
        for (int e = 0; e < 8; ++e) {
            { float v = wf0[e]; __bf16 hi = (__bf16)v; wh[0][e] = hi; wl[0][e] = (__bf16)(v - (float)hi); }
            { float v = wf1[e]; __bf16 hi = (__bf16)v; wh[1][e] = hi; wl[1][e] = (__bf16)(v - (float)hi); }
        }
        #pragma unroll
        for (int c = 0; c < 3; ++c)
            #pragma unroll
            for (int ot = 0; ot < 2; ++ot) {
                acc[c][ot] = MFMA(xh[c], wh[ot], acc[c][ot]);
                acc[c][ot] = MFMA(xl[c], wh[ot], acc[c][ot]);
                acc[c][ot] = MFMA(xh[c], wl[ot], acc[c][ot]);
            }
    }

    #pragma unroll
    for (int round = 0; round < 2; ++round) {
        __syncthreads();
        if ((w >> 1) == round) {
            unsigned int (*L)[196] = ldsr[w & 1];
            #pragma unroll
            for (int c = 0; c < 3; ++c)
                #pragma unroll
                for (int ot = 0; ot < 2; ++ot)
                    #pragma unroll
                    for (int r = 0; r < 16; ++r) {
                        float v = acc[c][ot][r];
                        if (part == 0) v *= (SCALE * LOG2E);
                        int nn = (r & 3) + 8 * (r >> 2) + 4 * hf;
                        int dcol = 3 * (ot * 32 + l31) + c;
                        L[nn][dcol] = (part == 2) ? (unsigned int)b16(v) : splitpack(v);
                    }
            if (part < 2) {
                const int itqw = blockIdx.y * 4 + w;
                u16* bhp = (part == 0 ? Qhi : Khi) + (size_t)bh * 393216 + itqw * 6144 + lane * 8;
                u16* blp = (part == 0 ? Qlo : Klo) + (size_t)bh * 393216 + itqw * 6144 + lane * 8;
                #pragma unroll
                for (int ks = 0; ks < 12; ++ks) {
                    const unsigned int* p = &L[l31][ks * 16 + hf * 8];
                    u32x4 a = *(const u32x4*)p;
                    u32x4 bq = *(const u32x4*)(p + 4);
                    u32x4 hi = { (a[0] & 0xffffu) | (a[1] << 16), (a[2] & 0xffffu) | (a[3] << 16),
                                 (bq[0] & 0xffffu) | (bq[1] << 16), (bq[2] & 0xffffu) | (bq[3] << 16) };
                    u32x4 lo = { (a[0] >> 16) | (a[1] & 0xffff0000u), (a[2] >> 16) | (a[3] & 0xffff0000u),
                                 (bq[0] >> 16) | (bq[1] & 0xffff0000u), (bq[2] >> 16) | (bq[3] & 0xffff0000u) };
                    *(u32x4*)(bhp + ks * 512) = hi;
                    *(u32x4*)(blp + ks * 512) = lo;
                }
            } else {
                const int jt = nw0 >> 6;
                u16* vp = Vf + (size_t)bh * 393216 + jt * 12288 + lane * 8;
                #pragma unroll
                for (int jkk = 0; jkk < 2; ++jkk) {
                    const int jk = ((nw0 >> 4) + jkk) & 3;
                    #pragma unroll
                    for (int dcf = 0; dcf < 6; ++dcf) {
                        unsigned int t[8];
                        #pragma unroll
                        for (int e = 0; e < 8; ++e)
                            t[e] = L[jkk * 16 + hf * 8 + e][dcf * 32 + l31];
                        u32x4 pk = { (t[0] & 0xffffu) | (t[1] << 16), (t[2] & 0xffffu) | (t[3] << 16),
                                     (t[4] & 0xffffu) | (t[5] << 16), (t[6] & 0xffffu) | (t[7] << 16) };
                        *(u32x4*)(vp + (jk * 6 + dcf) * 512) = pk;
                    }
                }
            }
        }
    }
}

// ---------------- K2: MFMA flash attention, j-split across blocks ------------
// grid 512 (flattened, XCD-swizzled), block 256 (4 waves; wave = one 32-row i-group)
// 8 independent S-chains (a=hi*hi, b=lo-corrections), global_load_lds dbuf staging.
__global__ __launch_bounds__(256, 1) void attn_mfma(
    const u16* __restrict__ Qhi, const u16* __restrict__ Qlo,
    const u16* __restrict__ Khi, const u16* __restrict__ Klo,
    const u16* __restrict__ Vf, u16* __restrict__ Opart, float* __restrict__ MLp) {
    __shared__ __align__(16) u16 lds[2][36864];  // dbuf: K_hi | K_lo | V per buffer
    const int tid = threadIdx.x;
    const int lane = tid & 63;
    const int w = tid >> 6;
    const int hf = lane >> 5;
    // XCD-aware decode: id%8 picks XCD; all 16 blocks of a (bh,half) group share one XCD.
    const int id = blockIdx.x;                     // 0..511
    const int rem = id >> 3;                       // 0..63
    const int g = ((rem >> 4) << 3) | (id & 7);    // 0..31: (bh,half) group
    const int i16 = rem & 15;                      // 0..15: i-tile group
    const int bh = g >> 1;
    const int half = g & 1;
    const int itq = i16 * 4 + w;

    bf16x8 qh[12], ql[12];
    {
        size_t qb = (((size_t)bh * 64 + itq) * 12 * 64 + lane) * 8;
        #pragma unroll
        for (int ks = 0; ks < 12; ++ks) {
            qh[ks] = *(const bf16x8*)(Qhi + qb + ks * 512);
            ql[ks] = *(const bf16x8*)(Qlo + qb + ks * 512);
        }
    }

    const char* gK = (const char*)Khi + (size_t)bh * 786432 + (size_t)half * 393216;
    const char* gL = (const char*)Klo + (size_t)bh * 786432 + (size_t)half * 393216;
    const char* gV = (const char*)Vf  + (size_t)bh * 786432 + (size_t)half * 393216;

    // async stage of one 64-j tile (Khi 24KB | Klo 24KB | V 24KB) into lds[buf]
    const int lsrc = w * 6144 + (lane << 4);
    auto stage = [&](int buf, int jt) {
        const size_t joff = (size_t)jt * 24576 + lsrc;
        char* dst = (char*)&lds[buf][0] + w * 6144;
        #pragma unroll
        for (int cc = 0; cc < 6; ++cc) {
            gload16(gK + joff + cc * 1024, dst + cc * 1024);
            gload16(gL + joff + cc * 1024, dst + 24576 + cc * 1024);
            gload16(gV + joff + cc * 1024, dst + 49152 + cc * 1024);
        }
    };

    stage(0, 0);
    __syncthreads();   // compiler drains vmcnt before s_barrier
    int cur = 0;

    f32x16 o[6] = {};
    float m_run = -1e30f, l_run = 0.f;

    for (int jt = 0; jt < 16; ++jt) {
        if (jt + 1 < 16) stage(cur ^ 1, jt + 1);   // async fill of next tile

        const u16* L = &lds[cur][0];
        // ---- S^T = K · Q^T : 8 independent accumulator chains ----
        f32x16 a00 = {}, a01 = {}, a10 = {}, a11 = {};
        f32x16 b00 = {}, b01 = {}, b10 = {}, b11 = {};
        #pragma unroll
        for (int mm = 0; mm < 6; ++mm) {
            const int k0 = mm * 2, k1 = mm * 2 + 1;
            bf16x8 kh00 = *(const bf16x8*)&L[(size_t)((k0) * 64 + lane) * 8];
            bf16x8 kh01 = *(const bf16x8*)&L[(size_t)((k1) * 64 + lane) * 8];
            bf16x8 kh10 = *(const bf16x8*)&L[(size_t)((12 + k0) * 64 + lane) * 8];
            bf16x8 kh11 = *(const bf16x8*)&L[(size_t)((12 + k1) * 64 + lane) * 8];
            bf16x8 kl00 = *(const bf16x8*)&L[12288 + (size_t)((k0) * 64 + lane) * 8];
            bf16x8 kl01 = *(const bf16x8*)&L[12288 + (size_t)((k1) * 64 + lane) * 8];
            bf16x8 kl10 = *(const bf16x8*)&L[12288 + (size_t)((12 + k0) * 64 + lane) * 8];
            bf16x8 kl11 = *(const bf16x8*)&L[12288 + (size_t)((12 + k1) * 64 + lane) * 8];
            a00 = MFMA(kh00, qh[k0], a00);
            b00 = MFMA(kh00, ql[k0], b00);
            a01 = MFMA(kh01, qh[k1], a01);
            b01 = MFMA(kh01, ql[k1], b01);
            a10 = MFMA(kh10, qh[k0], a10);
            b10 = MFMA(kh10, ql[k0], b10);
            a11 = MFMA(kh11, qh[k1], a11);
            b11 = MFMA(kh11, ql[k1], b11);
            b00 = MFMA(kl00, qh[k0], b00);
            b01 = MFMA(kl01, qh[k1], b01);
            b10 = MFMA(kl10, qh[k0], b10);
            b11 = MFMA(kl11, qh[k1], b11);
        }

        f32x16 sj0 = (a00 + a01) + (b00 + b01);
        f32x16 sj1 = (a10 + a11) + (b10 + b11);
        float pm = -1e30f;
        #pragma unroll
        for (int r = 0; r < 16; ++r) pm = fmaxf(pm, fmaxf(sj0[r], sj1[r]));
        pm = fmaxf(pm, __shfl_xor(pm, 32, 64));
        if (!__all(pm <= m_run + 8.0f)) {   // T13 defer-rescale (log2 domain)
            float mnew = fmaxf(m_run, pm);
            float sc = exp2f(m_run - mnew);
            l_run *= sc;
            #pragma unroll
            for (int d = 0; d < 6; ++d) o[d] = o[d] * sc;
            m_run = mnew;
        }
        float rs = 0.f;
        #pragma unroll
        for (int r = 0; r < 16; ++r) {
            sj0[r] = exp2f(sj0[r] - m_run); rs += sj0[r];
            sj1[r] = exp2f(sj1[r] - m_run); rs += sj1[r];
        }
        rs += __shfl_xor(rs, 32, 64);
        l_run += rs;

        bf16x8 pf[4];
        {
            unsigned int pk[8], X[8];
            #pragma unroll
            for (int g2 = 0; g2 < 8; ++g2) {
                pk[g2] = pack2(sj0[2 * g2], sj0[2 * g2 + 1]);
                X[g2] = (unsigned int)__shfl_xor((int)pk[g2], 32, 64);
            }
            u32x4 f0 = {hf ? X[2] : pk[0], hf ? X[3] : pk[1], hf ? pk[2] : X[0], hf ? pk[3] : X[1]};
            u32x4 f1 = {hf ? X[6] : pk[4], hf ? X[7] : pk[5], hf ? pk[6] : X[4], hf ? pk[7] : X[5]};
            pf[0] = __builtin_bit_cast(bf16x8, f0);
            pf[1] = __builtin_bit_cast(bf16x8, f1);
            #pragma unroll
            for (int g2 = 0; g2 < 8; ++g2) {
                pk[g2] = pack2(sj1[2 * g2], sj1[2 * g2 + 1]);
                X[g2] = (unsigned int)__shfl_xor((int)pk[g2], 32, 64);
            }
            u32x4 f2 = {hf ? X[2] : pk[0], hf ? X[3] : pk[1], hf ? pk[2] : X[0], hf ? pk[3] : X[1]};
            u32x4 f3 = {hf ? X[6] : pk[4], hf ? X[7] : pk[5], hf ? pk[6] : X[4], hf ? pk[7] : X[5]};
            pf[2] = __builtin_bit_cast(bf16x8, f2);
            pf[3] = __builtin_bit_cast(bf16x8, f3);
        }

        #pragma unroll
        for (int jk = 0; jk < 4; ++jk)
            #pragma unroll
            for (int d = 0; d < 6; ++d) {
                bf16x8 vf = *(const bf16x8*)&L[24576 + (size_t)((jk * 6 + d) * 64 + lane) * 8];
                o[d] = MFMA(vf, pf[jk], o[d]);
            }

        if (jt + 1 < 16) {
            __syncthreads();   // next tile staged (vmcnt drained) + all reads of cur done
            cur ^= 1;
        }
    }

    // ---- epilogue: write unnormalized bf16 partial O + (m,l) ----
    const int tI = bh * 64 + itq;
    u16* Op = Opart + ((size_t)(half * 1024 + tI) * 96) * 64 + lane;
    #pragma unroll
    for (int d = 0; d < 6; ++d)
        #pragma unroll
        for (int r = 0; r < 16; ++r)
            Op[(d * 16 + r) * 64] = b16(o[d][r]);
    float* mlp = MLp + (size_t)(half * 1024 + tI) * 128 + lane * 2;
    mlp[0] = m_run;
    mlp[1] = l_run;
}

// ---------------- K2b: combine j-halves -> att2 (split-pack frag layout) -----
__global__ __launch_bounds__(256) void attn_combine(const u16* __restrict__ Opart,
                                                    const float* __restrict__ MLp,
                                                    unsigned int* __restrict__ att2) {
    const int tid = threadIdx.x, lane = tid & 63, w = tid >> 6, hf = lane >> 5;
    const int tI = blockIdx.x * 4 + w;     // 0..1023
    const int bh = tI >> 6, itq = tI & 63;
    const float* mla = MLp + (size_t)tI * 128 + lane * 2;
    const float* mlb = MLp + (size_t)(1024 + tI) * 128 + lane * 2;
    float ma = mla[0], la = mla[1];
    float mb = mlb[0], lb = mlb[1];
    float mm = fmaxf(ma, mb);
    float wa = exp2f(ma - mm), wb = exp2f(mb - mm);
    float inv = 1.0f / (la * wa + lb * wb);
    const u16* Oa = Opart + ((size_t)tI * 96) * 64 + lane;
    const u16* Ob = Opart + ((size_t)(1024 + tI) * 96) * 64 + lane;
    const int b2 = bh >> 3, hh = bh & 7;
    const int i31 = lane & 31;
    #pragma unroll
    for (int d = 0; d < 6; ++d)
        #pragma unroll
        for (int r = 0; r < 16; ++r) {
            float va = fb16(Oa[(d * 16 + r) * 64]);
            float vb = fb16(Ob[(d * 16 + r) * 64]);
            float v = (va * wa + vb * wb) * inv;
            int dc = d * 32 + (r & 3) + 8 * (r >> 2) + 4 * hf;
            int dd = dc / 3, cc = dc - dd * 3;
            int hd = hh * 64 + dd;
            int ks = hd >> 4, e = hd & 7;
            int ln = i31 | (((hd >> 3) & 1) << 5);
            size_t off = ((((size_t)(b2 * 3 + cc) * 32 + ks) * 64 + itq) * 512 + (size_t)ln * 8 + e);
            att2[off] = splitpack(v);
        }
}

// ---------------- K3: output projection, MFMA split-bf16, no LDS ----------------
__global__ __launch_bounds__(256) void out_mfma(const unsigned int* __restrict__ att2,
                                                const float* __restrict__ wo,
                                                float* __restrict__ out) {
    const int tid = threadIdx.x, lane = tid & 63, w = tid >> 6, hf = lane >> 5, l31 = lane & 31;
    const int o0 = blockIdx.x * 32;
    const int n5 = blockIdx.y * 4 + w;
    const int b = blockIdx.z;
    const float* wp = wo + (size_t)(o0 + l31) * 512 + hf * 8;
    const unsigned int* ap = att2 + ((size_t)(b * 3) * 2048 + n5) * 512 + (size_t)lane * 8;
    f32x16 acc[3] = {};
    #pragma unroll 2
    for (int ks = 0; ks < 32; ++ks) {
        bf16x8 wh, wl;
        {
            f32x4v t0 = *(const f32x4v*)(wp + ks * 16);
            f32x4v t1 = *(const f32x4v*)(wp + ks * 16 + 4);
            #pragma unroll
            for (int e = 0; e < 4; ++e) {
                { float v = t0[e]; __bf16 hi = (__bf16)v; wh[e] = hi; wl[e] = (__bf16)(v - (float)hi); }
                { float v = t1[e]; __bf16 hi = (__bf16)v; wh[4 + e] = hi; wl[4 + e] = (__bf16)(v - (float)hi); }
            }
        }
        #pragma unroll
        for (int c = 0; c < 3; ++c) {
            const unsigned int* pc = ap + (size_t)c * 1048576 + ks * 32768;
            u32x4 a0 = *(const u32x4*)pc;
            u32x4 a1 = *(const u32x4*)(pc + 4);
            union { bf16x8 v; u32x4 u; } H, Lo;
            H.u  = { (a0[0] & 0xffffu) | (a0[1] << 16), (a0[2] & 0xffffu) | (a0[3] << 16),
                     (a1[0] & 0xffffu) | (a1[1] << 16), (a1[2] & 0xffffu) | (a1[3] << 16) };
            Lo.u = { (a0[0] >> 16) | (a0[1] & 0xffff0000u), (a0[2] >> 16) | (a0[3] & 0xffff0000u),
                     (a1[0] >> 16) | (a1[1] & 0xffff0000u), (a1[2] >> 16) | (a1[3] & 0xffff0000u) };
            acc[c] = MFMA(H.v, wh, acc[c]);
            acc[c] = MFMA(Lo.v, wh, acc[c]);
            acc[c] = MFMA(H.v, wl, acc[c]);
        }
    }
    #pragma unroll
    for (int r = 0; r < 16; ++r) {
        int n = (n5 << 5) + (r & 3) + 8 * (r >> 2) + 4 * hf;
        size_t off = ((size_t)(b * 2048 + n) * 256 + o0 + l31) * 3;
        out[off]     = acc[0][r];
        out[off + 1] = acc[1][r];
        out[off + 2] = acc[2][r];
    }
}

extern "C" void kernel_launch(void* const* d_in, const int* in_sizes, int n_in,
                              void* d_out, int out_size, void* d_ws, size_t ws_size,
                              hipStream_t stream) {
    const float* x     = (const float*)d_in[0];
    const float* w_qkv = (const float*)d_in[1];
    const float* w_out = (const float*)d_in[2];
    float* out = (float*)d_out;

    const size_t NB = (size_t)16 * 2048 * 192;  // 6.29M elems
    u16* Qhi = (u16*)d_ws;
    u16* Qlo = Qhi + NB;
    u16* Khi = Qlo + NB;
    u16* Klo = Khi + NB;
    u16* Vf  = Klo + NB;
    u16* Opart = Vf + NB;                       // 2*NB u16 = 25.2MB
    float* MLp = (float*)(Opart + 2 * NB);      // 262144 floats = 1MB
    unsigned int* att2 = (unsigned int*)Qhi;    // reuses Qhi+Qlo (dead after attn)

    qkv_mfma<<<dim3(24, 16, 2), 256, 0, stream>>>(x, w_qkv, Qhi, Qlo, Khi, Klo, Vf);
    attn_mfma<<<dim3(512), 256, 0, stream>>>(Qhi, Qlo, Khi, Klo, Vf, Opart, MLp);
    attn_combine<<<dim3(256), 256, 0, stream>>>(Opart, MLp, att2);
    out_mfma<<<dim3(8, 16, 2), 256, 0, stream>>>(att2, w_out, out);
}

// Round 8
// 225.590 us; speedup vs baseline: 1.3626x; 1.3626x over previous
//
#include <hip/hip_runtime.h>
#include <hip/hip_bf16.h>

#define SCALE 0.07216878364870322f   // (3*64)^-0.5
#define LOG2E 1.4426950408889634f
// Q is pre-scaled by SCALE*LOG2E so attention logits are in log2 units.

typedef __bf16 bf16x8 __attribute__((ext_vector_type(8)));
typedef float f32x16 __attribute__((ext_vector_type(16)));
typedef float f32x4v __attribute__((ext_vector_type(4)));
typedef unsigned int u32x4 __attribute__((ext_vector_type(4)));
typedef unsigned short u16;

#define MFMA(a, b, c) __builtin_amdgcn_mfma_f32_32x32x16_bf16(a, b, c, 0, 0, 0)
#define MFMA16(a, b, c) __builtin_amdgcn_mfma_f32_16x16x32_bf16(a, b, c, 0, 0, 0)

__device__ __forceinline__ u16 b16(float v) { return __builtin_bit_cast(u16, (__bf16)v); }
__device__ __forceinline__ float fb16(u16 u) {
    unsigned int t = (unsigned int)u << 16;
    return __builtin_bit_cast(float, t);
}
__device__ __forceinline__ unsigned int splitpack(float v) {
    u16 h = b16(v);
    float r = v - fb16(h);
    return (unsigned int)h | ((unsigned int)b16(r) << 16);
}
__device__ __forceinline__ unsigned int pack2(float a, float b) {
    return (unsigned int)b16(a) | ((unsigned int)b16(b) << 16);
}
__device__ __forceinline__ void gload16(const void* g, void* l) {
    __builtin_amdgcn_global_load_lds((const __attribute__((address_space(1))) void*)g,
                                     (__attribute__((address_space(3))) void*)l, 16, 0, 0);
}

// ---------------- K1: QKV projection, MFMA split-bf16, zero-LDS main loop ----
// Emits 16x16x32-frag-major layouts:
//  Q (B-frag): off = ((bh*128 + i16)*6 + kc)*512 + lane*8 + e   lane=(i&15)|((kk>>3)<<4), e=kk&7
//  K (A-frag): off = ((bh*32+jt)*24 + (jsub*6+kc))*512 + lane*8 + e  lane=(j&15)|((kk>>3)<<4)
//  V (A-frag V^T): off = ((bh*32+jt)*24 + (dcsub*2+jc))*512 + lane*8 + e  lane=(dc&15)|((jj>>3)<<4)
__global__ __launch_bounds__(256) void qkv_mfma(const float* __restrict__ x,
                                                const float* __restrict__ wq,
                                                u16* __restrict__ Qhi, u16* __restrict__ Qlo,
                                                u16* __restrict__ Khi, u16* __restrict__ Klo,
                                                u16* __restrict__ Vf) {
    __shared__ unsigned int ldsr[2][32][196];
    const int tid = threadIdx.x;
    const int lane = tid & 63, w = tid >> 6, hf = lane >> 5, l31 = lane & 31;
    const int lq = lane & 15, gq = lane >> 4;   // 16x16-frag coords
    const int o0 = blockIdx.x * 64;
    const int n0 = blockIdx.y * 128;
    const int b = blockIdx.z;
    const int nw0 = n0 + w * 32;
    const int part = o0 >> 9;
    const int h = (o0 >> 6) & 7;
    const int bh = b * 8 + h;

    const float* xp = x + ((size_t)(b * 2048 + nw0 + l31)) * 768 + hf * 24;
    const float* wp0 = wq + (size_t)(o0 + l31) * 256 + hf * 8;
    const float* wp1 = wp0 + 32 * 256;

    f32x16 acc[3][2] = {};
    #pragma unroll 2
    for (int k0 = 0; k0 < 16; ++k0) {
        float xf[24], wf0[8], wf1[8];
        #pragma unroll
        for (int q = 0; q < 6; ++q) {
            f32x4v t = *(const f32x4v*)(xp + k0 * 48 + q * 4);
            xf[q * 4 + 0] = t[0]; xf[q * 4 + 1] = t[1];
            xf[q * 4 + 2] = t[2]; xf[q * 4 + 3] = t[3];
        }
        {
            f32x4v t0 = *(const f32x4v*)(wp0 + k0 * 16);
            f32x4v t1 = *(const f32x4v*)(wp0 + k0 * 16 + 4);
            f32x4v t2 = *(const f32x4v*)(wp1 + k0 * 16);
            f32x4v t3 = *(const f32x4v*)(wp1 + k0 * 16 + 4);
            #pragma unroll
            for (int e = 0; e < 4; ++e) {
                wf0[e] = t0[e]; wf0[4 + e] = t1[e];
                wf1[e] = t2[e]; wf1[4 + e] = t3[e];
            }
        }
        bf16x8 xh[3], xl[3], wh[2], wl[2];
        #pragma unroll
        for (int c = 0; c < 3; ++c)
            #pragma unroll
            for (int e = 0; e < 8; ++e) {
                float v = xf[e * 3 + c];
                __bf16 hi = (__bf16)v;
                xh[c][e] = hi;
                xl[c][e] = (__bf16)(v - (float)hi);
            }
        #pragma unroll
        for (int e = 0; e < 8; ++e) {
            { float v = wf0[e]; __bf16 hi = (__bf16)v; wh[0][e] = hi; wl[0][e] = (__bf16)(v - (float)hi); }
            { float v = wf1[e]; __bf16 hi = (__bf16)v; wh[1][e] = hi; wl[1][e] = (__bf16)(v - (float)hi); }
        }
        #pragma unroll
        for (int c = 0; c < 3; ++c)
            #pragma unroll
            for (int ot = 0; ot < 2; ++ot) {
                acc[c][ot] = MFMA(xh[c], wh[ot], acc[c][ot]);
                acc[c][ot] = MFMA(xl[c], wh[ot], acc[c][ot]);
                acc[c][ot] = MFMA(xh[c], wl[ot], acc[c][ot]);
            }
    }

    #pragma unroll
    for (int round = 0; round < 2; ++round) {
        __syncthreads();
        if ((w >> 1) == round) {
            unsigned int (*L)[196] = ldsr[w & 1];
            #pragma unroll
            for (int c = 0; c < 3; ++c)
                #pragma unroll
                for (int ot = 0; ot < 2; ++ot)
                    #pragma unroll
                    for (int r = 0; r < 16; ++r) {
                        float v = acc[c][ot][r];
                        if (part == 0) v *= (SCALE * LOG2E);
                        int nn = (r & 3) + 8 * (r >> 2) + 4 * hf;
                        int dcol = 3 * (ot * 32 + l31) + c;
                        L[nn][dcol] = (part == 2) ? (unsigned int)b16(v) : splitpack(v);
                    }
            if (part < 2) {
                const int jt = nw0 >> 6;
                u16* baseH = (part == 0 ? Qhi : Khi);
                u16* baseL = (part == 0 ? Qlo : Klo);
                #pragma unroll
                for (int is = 0; is < 2; ++is)
                    #pragma unroll
                    for (int kc = 0; kc < 6; ++kc) {
                        const unsigned int* p = &L[is * 16 + lq][kc * 32 + gq * 8];
                        u32x4 a = *(const u32x4*)p;
                        u32x4 bq = *(const u32x4*)(p + 4);
                        u32x4 hi = { (a[0] & 0xffffu) | (a[1] << 16), (a[2] & 0xffffu) | (a[3] << 16),
                                     (bq[0] & 0xffffu) | (bq[1] << 16), (bq[2] & 0xffffu) | (bq[3] << 16) };
                        u32x4 lo = { (a[0] >> 16) | (a[1] & 0xffff0000u), (a[2] >> 16) | (a[3] & 0xffff0000u),
                                     (bq[0] >> 16) | (bq[1] & 0xffff0000u), (bq[2] >> 16) | (bq[3] & 0xffff0000u) };
                        size_t off;
                        if (part == 0)
                            off = ((size_t)(bh * 128 + (nw0 >> 4) + is) * 6 + kc) * 512 + lane * 8;
                        else
                            off = ((size_t)(bh * 32 + jt) * 24 + ((((nw0 >> 4) & 3) + is) * 6 + kc)) * 512 + lane * 8;
                        *(u32x4*)(baseH + off) = hi;
                        *(u32x4*)(baseL + off) = lo;
                    }
            } else {
                const int jt = nw0 >> 6, jc = (nw0 >> 5) & 1;
                u16* vp = Vf + ((size_t)(bh * 32 + jt) * 24 + jc) * 512 + lane * 8;
                #pragma unroll
                for (int d = 0; d < 12; ++d) {
                    unsigned int t[8];
                    #pragma unroll
                    for (int e = 0; e < 8; ++e)
                        t[e] = L[gq * 8 + e][d * 16 + lq];
                    u32x4 pk = { (t[0] & 0xffffu) | (t[1] << 16), (t[2] & 0xffffu) | (t[3] << 16),
                                 (t[4] & 0xffffu) | (t[5] << 16), (t[6] & 0xffffu) | (t[7] << 16) };
                    *(u32x4*)(vp + d * 1024) = pk;
                }
            }
        }
    }
}

// ---------------- K2: MFMA flash attention, 16x16x32, 8 waves, full j-range --
// grid 256 (XCD-swizzled), block 512: wave w owns 16 i-rows; K/V dbuf via global_load_lds.
__global__ __launch_bounds__(512) void attn_mfma(
    const u16* __restrict__ Qhi, const u16* __restrict__ Qlo,
    const u16* __restrict__ Khi, const u16* __restrict__ Klo,
    const u16* __restrict__ Vf, unsigned int* __restrict__ att2) {
    __shared__ __align__(16) u16 lds[2][36864];  // per buf: Khi[12288]|Klo[12288]|V[12288]
    const int tid = threadIdx.x;
    const int lane = tid & 63;
    const int w = tid >> 6;          // 0..7
    const int g = lane >> 4;         // 0..3
    const int i = lane & 15;
    // XCD swizzle: 16 blocks sharing a bh's K/V slab land on one XCD (bijective).
    const int id = blockIdx.x;                 // 0..255
    const int bh = (id & 7) * 2 + (id >> 7);
    const int itile = (id >> 3) & 15;
    const int i0 = itile * 128 + w * 16;

    // Q B-frags resident (hi+lo): 48 VGPRs
    bf16x8 qh[6], ql[6];
    {
        size_t qb = ((size_t)(bh * 128 + (i0 >> 4)) * 6) * 512 + (size_t)lane * 8;
        #pragma unroll
        for (int kc = 0; kc < 6; ++kc) {
            qh[kc] = *(const bf16x8*)(Qhi + qb + kc * 512);
            ql[kc] = *(const bf16x8*)(Qlo + qb + kc * 512);
        }
    }

    const char* gK = (const char*)Khi + (size_t)bh * 786432;
    const char* gL = (const char*)Klo + (size_t)bh * 786432;
    const char* gV = (const char*)Vf + (size_t)bh * 786432;
    const int t16 = tid * 16;

    auto stage = [&](int buf, int jt) {
        const size_t jo = (size_t)jt * 24576 + t16;
        char* dst = (char*)&lds[buf][0] + t16;
        #pragma unroll
        for (int s = 0; s < 3; ++s) {
            gload16(gK + jo + s * 8192, dst + s * 8192);
            gload16(gL + jo + s * 8192, dst + 24576 + s * 8192);
            gload16(gV + jo + s * 8192, dst + 49152 + s * 8192);
        }
    };

    stage(0, 0);
    __syncthreads();
    int cur = 0;

    f32x4v o[12] = {};
    float m_run = -1e30f, l_run = 0.f;
    const int sl0 = ((g & 1) << 5) + i;
    const int sl1 = sl0 + 16;
    const bool ghi = (g >> 1) != 0;

    for (int jt = 0; jt < 32; ++jt) {
        if (jt + 1 < 32) stage(cur ^ 1, jt + 1);
        const u16* L = &lds[cur][0];

        // ---- S^T = K · Q^T (3-term split, 4 jsub-interleaved chains) ----
        f32x4v s4[4] = {};
        #pragma unroll
        for (int kc = 0; kc < 6; ++kc) {
            bf16x8 kh[4], kl[4];
            #pragma unroll
            for (int js = 0; js < 4; ++js) {
                kh[js] = *(const bf16x8*)&L[(unsigned)((js * 6 + kc) * 512) + lane * 8];
                kl[js] = *(const bf16x8*)&L[12288u + (unsigned)((js * 6 + kc) * 512) + lane * 8];
            }
            #pragma unroll
            for (int js = 0; js < 4; ++js) s4[js] = MFMA16(kh[js], qh[kc], s4[js]);
            #pragma unroll
            for (int js = 0; js < 4; ++js) s4[js] = MFMA16(kh[js], ql[kc], s4[js]);
            #pragma unroll
            for (int js = 0; js < 4; ++js) s4[js] = MFMA16(kl[js], qh[kc], s4[js]);
        }

        // ---- online softmax (log2 domain), rows lane-replicated x4 ----
        float pm = -1e30f;
        #pragma unroll
        for (int js = 0; js < 4; ++js)
            #pragma unroll
            for (int r = 0; r < 4; ++r) pm = fmaxf(pm, s4[js][r]);
        pm = fmaxf(pm, __shfl_xor(pm, 16, 64));
        pm = fmaxf(pm, __shfl_xor(pm, 32, 64));
        if (!__all(pm <= m_run + 8.0f)) {   // T13 defer-rescale
            float mnew = fmaxf(m_run, pm);
            float sc = exp2f(m_run - mnew);
            l_run *= sc;
            #pragma unroll
            for (int d = 0; d < 12; ++d) o[d] = o[d] * sc;
            m_run = mnew;
        }
        float rs = 0.f;
        unsigned int w0[4], w1[4];
        #pragma unroll
        for (int js = 0; js < 4; ++js) {
            float p0 = exp2f(s4[js][0] - m_run), p1 = exp2f(s4[js][1] - m_run);
            float p2 = exp2f(s4[js][2] - m_run), p3 = exp2f(s4[js][3] - m_run);
            rs += (p0 + p1) + (p2 + p3);
            w0[js] = pack2(p0, p1);
            w1[js] = pack2(p2, p3);
        }
        rs += __shfl_xor(rs, 16, 64);
        rs += __shfl_xor(rs, 32, 64);
        l_run += rs;

        // ---- O^T += V^T · P^T : P B-frags built by group shuffles ----
        #pragma unroll
        for (int c = 0; c < 2; ++c) {
            u32x4 F;
            { unsigned a0 = __shfl((int)w0[2 * c], sl0, 64), a1 = __shfl((int)w0[2 * c + 1], sl0, 64); F[0] = ghi ? a1 : a0; }
            { unsigned a0 = __shfl((int)w1[2 * c], sl0, 64), a1 = __shfl((int)w1[2 * c + 1], sl0, 64); F[1] = ghi ? a1 : a0; }
            { unsigned a0 = __shfl((int)w0[2 * c], sl1, 64), a1 = __shfl((int)w0[2 * c + 1], sl1, 64); F[2] = ghi ? a1 : a0; }
            { unsigned a0 = __shfl((int)w1[2 * c], sl1, 64), a1 = __shfl((int)w1[2 * c + 1], sl1, 64); F[3] = ghi ? a1 : a0; }
            bf16x8 pb = __builtin_bit_cast(bf16x8, F);
            #pragma unroll
            for (int d = 0; d < 12; ++d) {
                bf16x8 vf = *(const bf16x8*)&L[24576u + (unsigned)((d * 2 + c) * 512) + lane * 8];
                o[d] = MFMA16(vf, pb, o[d]);
            }
        }

        if (jt + 1 < 32) {
            __syncthreads();   // drains vmcnt: next buffer staged; cur reads done
            cur ^= 1;
        }
    }

    // ---- epilogue: att2 split-pack A-frag-major (same layout as before) ----
    float inv = 1.0f / l_run;
    const int b2 = bh >> 3, hh = bh & 7;
    const int ig = i0 + i;
    const int itq = ig >> 5, i31 = ig & 31;
    #pragma unroll
    for (int d = 0; d < 12; ++d)
        #pragma unroll
        for (int r = 0; r < 4; ++r) {
            int dc = d * 16 + g * 4 + r;
            int dd = dc / 3, cc2 = dc - dd * 3;
            int hd = hh * 64 + dd;
            int ks = hd >> 4, e = hd & 7;
            int ln = i31 | (((hd >> 3) & 1) << 5);
            size_t off = (((size_t)(b2 * 3 + cc2) * 32 + ks) * 64 + itq) * 512 + (size_t)ln * 8 + e;
            att2[off] = splitpack(o[d][r] * inv);
        }
}

// ---------------- K3: output projection, MFMA split-bf16, no LDS ----------------
__global__ __launch_bounds__(256) void out_mfma(const unsigned int* __restrict__ att2,
                                                const float* __restrict__ wo,
                                                float* __restrict__ out) {
    const int tid = threadIdx.x, lane = tid & 63, w = tid >> 6, hf = lane >> 5, l31 = lane & 31;
    const int o0 = blockIdx.x * 32;
    const int n5 = blockIdx.y * 4 + w;
    const int b = blockIdx.z;
    const float* wp = wo + (size_t)(o0 + l31) * 512 + hf * 8;
    const unsigned int* ap = att2 + ((size_t)(b * 3) * 2048 + n5) * 512 + (size_t)lane * 8;
    f32x16 acc[3] = {};
    #pragma unroll 2
    for (int ks = 0; ks < 32; ++ks) {
        bf16x8 wh, wl;
        {
            f32x4v t0 = *(const f32x4v*)(wp + ks * 16);
            f32x4v t1 = *(const f32x4v*)(wp + ks * 16 + 4);
            #pragma unroll
            for (int e = 0; e < 4; ++e) {
                { float v = t0[e]; __bf16 hi = (__bf16)v; wh[e] = hi; wl[e] = (__bf16)(v - (float)hi); }
                { float v = t1[e]; __bf16 hi = (__bf16)v; wh[4 + e] = hi; wl[4 + e] = (__bf16)(v - (float)hi); }
            }
        }
        #pragma unroll
        for (int c = 0; c < 3; ++c) {
            const unsigned int* pc = ap + (size_t)c * 1048576 + ks * 32768;
            u32x4 a0 = *(const u32x4*)pc;
            u32x4 a1 = *(const u32x4*)(pc + 4);
            union { bf16x8 v; u32x4 u; } H, Lo;
            H.u  = { (a0[0] & 0xffffu) | (a0[1] << 16), (a0[2] & 0xffffu) | (a0[3] << 16),
                     (a1[0] & 0xffffu) | (a1[1] << 16), (a1[2] & 0xffffu) | (a1[3] << 16) };
            Lo.u = { (a0[0] >> 16) | (a0[1] & 0xffff0000u), (a0[2] >> 16) | (a0[3] & 0xffff0000u),
                     (a1[0] >> 16) | (a1[1] & 0xffff0000u), (a1[2] >> 16) | (a1[3] & 0xffff0000u) };
            acc[c] = MFMA(H.v, wh, acc[c]);
            acc[c] = MFMA(Lo.v, wh, acc[c]);
            acc[c] = MFMA(H.v, wl, acc[c]);
        }
    }
    #pragma unroll
    for (int r = 0; r < 16; ++r) {
        int n = (n5 << 5) + (r & 3) + 8 * (r >> 2) + 4 * hf;
        size_t off = ((size_t)(b * 2048 + n) * 256 + o0 + l31) * 3;
        out[off]     = acc[0][r];
        out[off + 1] = acc[1][r];
        out[off + 2] = acc[2][r];
    }
}

extern "C" void kernel_launch(void* const* d_in, const int* in_sizes, int n_in,
                              void* d_out, int out_size, void* d_ws, size_t ws_size,
                              hipStream_t stream) {
    const float* x     = (const float*)d_in[0];
    const float* w_qkv = (const float*)d_in[1];
    const float* w_out = (const float*)d_in[2];
    float* out = (float*)d_out;

    const size_t NB = (size_t)16 * 2048 * 192;  // 6.29M elems
    u16* Qhi = (u16*)d_ws;
    u16* Qlo = Qhi + NB;
    u16* Khi = Qlo + NB;
    u16* Klo = Khi + NB;
    u16* Vf  = Klo + NB;
    unsigned int* att2 = (unsigned int*)(Vf + NB);   // NB u32 = 25.2MB

    qkv_mfma<<<dim3(24, 16, 2), 256, 0, stream>>>(x, w_qkv, Qhi, Qlo, Khi, Klo, Vf);
    attn_mfma<<<dim3(256), 512, 0, stream>>>(Qhi, Qlo, Khi, Klo, Vf, att2);
    out_mfma<<<dim3(8, 16, 2), 256, 0, stream>>>(att2, w_out, out);
}